// Round 6
// baseline (1385.001 us; speedup 1.0000x reference)
//
#include <hip/hip_runtime.h>

#define D 48
#define C 16
#define H 128
#define D3 (D*D*D)
#define NVOX (2*D3)           // 221184
#define NB_FC (NVOX/256)      // 864
#define BN_EPS 1e-5f

typedef unsigned short u16;
typedef unsigned int   u32;

__device__ __forceinline__ float bf2f(u16 u) {
    union { u32 i; float f; } p; p.i = ((u32)u) << 16; return p.f;
}
__device__ __forceinline__ u16 f2bf(float f) {
    union { float f; u32 i; } p; p.f = f;
    u32 r = p.i + 0x7fffu + ((p.i >> 16) & 1u);   // RTNE
    return (u16)(r >> 16);
}
__device__ __forceinline__ int refl(int i) {
    return i < 0 ? -i : (i >= D ? 2*D - 2 - i : i);
}
__device__ __forceinline__ void fma4(float4& a, float s, const float4 w) {
    a.x = fmaf(s, w.x, a.x); a.y = fmaf(s, w.y, a.y);
    a.z = fmaf(s, w.z, a.z); a.w = fmaf(s, w.w, a.w);
}

// ---------------------------------------------------------------------------
// k_xpose: x channels-last [v][c] -> xt channel-major [b][c][s]. Once, step 0.
// ---------------------------------------------------------------------------
__global__ __launch_bounds__(256)
void k_xpose(const float* __restrict__ x, float* __restrict__ xt) {
    __shared__ float s[16][68];
    const int t = threadIdx.x;
    const size_t vb = (size_t)blockIdx.x * 64;
    float4 v4 = ((const float4*)(x + vb*16))[t];
    const int vv = t >> 2, c0 = (t & 3) * 4;
    s[c0+0][vv] = v4.x; s[c0+1][vv] = v4.y; s[c0+2][vv] = v4.z; s[c0+3][vv] = v4.w;
    __syncthreads();
    const int c = t >> 4, i0 = (t & 15) * 4;
    const size_t b = vb / D3, sp = vb % D3;
    float4 o = { s[c][i0], s[c][i0+1], s[c][i0+2], s[c][i0+3] };
    *(float4*)(xt + (b*16 + c)*(size_t)D3 + sp + i0) = o;
}

// ---------------------------------------------------------------------------
// k_wxpose: conv weights [kidx][c] -> wt[c][dy][dz][dx]. Run once.
// ---------------------------------------------------------------------------
__global__ __launch_bounds__(256)
void k_wxpose(const float* __restrict__ cw, float* __restrict__ wt) {
    int i = blockIdx.x * 256 + threadIdx.x;
    if (i < 343 * 16) {
        int kidx = i >> 4, c = i & 15;           // kidx = (dz*7+dy)*7+dx
        int dz = kidx / 49, dy = (kidx / 7) % 7, dx = kidx % 7;
        wt[((c*7 + dy)*7 + dz)*7 + dx] = cw[i];
    }
}

// ---------------------------------------------------------------------------
// k_conv v4: z-tile 3 (grid 1536 -> 6 blocks/CU, 18 waves/CU) + hoisted
// staging addressing (per-thread off/lds-word pairs precomputed once) +
// issue-early/write-late plane staging so global latency hides under FMAs.
// 12 register accumulators (3 z x 4 x) per thread; 9 planes per block.
// ---------------------------------------------------------------------------
#define CTPB 192
#define PLW (22*60)           // LDS words per plane buffer
__global__ __launch_bounds__(CTPB)
void k_conv(const float* __restrict__ xt, const float* __restrict__ wt,
            const float* __restrict__ cbias, u16* __restrict__ y1) {
    __shared__ float pl[2][PLW];      // 10560 B
    const int bid = blockIdx.x;
    const int zt = bid & 15;          // 16 z-tiles of 3
    const int yt = (bid >> 4) % 3;    // 3 y-tiles of 16
    const int c  = (bid / 48) & 15;
    const int b  = bid / 768;
    const int t  = threadIdx.x;
    const int tx = t % 12, ty = t / 12;
    const int y0 = yt * 16, z0 = zt * 3;
    const float* xb = xt + ((size_t)b*16 + c) * D3;
    const float* wc = wt + c * 343;   // [dy][dz][dx]

    // hoisted staging addressing: slot s covers idx = t + 192*s of the
    // 22x54 plane tile; off = global word offset in plane, lw = LDS word.
    int off[7], lw[7];
    #pragma unroll
    for (int s = 0; s < 7; ++s) {
        const int idx = t + CTPB*s;
        if (idx < 22*54) {
            const int r  = idx / 54;
            const int jc = idx - r*54;
            off[s] = refl(y0 - 3 + r)*D + refl(jc - 3);
            lw[s]  = r*60 + jc + 1;
        } else { off[s] = 0; lw[s] = -1; }
    }

    float a[3][4];
    #pragma unroll
    for (int k = 0; k < 3; ++k)
        a[k][0] = a[k][1] = a[k][2] = a[k][3] = 0.f;

    {   // prologue: stage plane z0-3
        const float* src = xb + (size_t)refl(z0-3) * (D*D);
        float* Q = pl[(z0-3) & 1];
        #pragma unroll
        for (int s = 0; s < 7; ++s)
            if (lw[s] >= 0) Q[lw[s]] = src[off[s]];
    }
    __syncthreads();

    for (int zi = z0 - 3; zi <= z0 + 5; ++zi) {
        // issue next plane's global loads early (latency hides under FMAs)
        float nv[7];
        const bool have = (zi < z0 + 5);
        if (have) {
            const float* src = xb + (size_t)refl(zi+1) * (D*D);
            #pragma unroll
            for (int s = 0; s < 7; ++s)
                if (lw[s] >= 0) nv[s] = src[off[s]];
        }
        const float* P = pl[zi & 1];
        #pragma unroll
        for (int dy = 0; dy < 7; ++dy) {
            const float* rp = P + (ty+dy)*60 + 4*tx;   // 16B aligned
            float4 A  = *(const float4*)rp;
            float4 Bv = *(const float4*)(rp + 4);
            float4 Cv = *(const float4*)(rp + 8);
            #pragma unroll
            for (int k = 0; k < 3; ++k) {        // output z = z0+k
                const int dz = zi - z0 - k + 3;  // block-uniform
                if (dz >= 0 && dz <= 6) {        // scalar branch
                    const float* wp = wc + (dy*7 + dz)*7;
                    float w0=wp[0], w1=wp[1], w2=wp[2], w3=wp[3];
                    float w4=wp[4], w5=wp[5], w6=wp[6];
                    a[k][0] = fmaf(w0,A.y, fmaf(w1,A.z, fmaf(w2,A.w, fmaf(w3,Bv.x,
                              fmaf(w4,Bv.y, fmaf(w5,Bv.z, fmaf(w6,Bv.w, a[k][0])))))));
                    a[k][1] = fmaf(w0,A.z, fmaf(w1,A.w, fmaf(w2,Bv.x, fmaf(w3,Bv.y,
                              fmaf(w4,Bv.z, fmaf(w5,Bv.w, fmaf(w6,Cv.x, a[k][1])))))));
                    a[k][2] = fmaf(w0,A.w, fmaf(w1,Bv.x, fmaf(w2,Bv.y, fmaf(w3,Bv.z,
                              fmaf(w4,Bv.w, fmaf(w5,Cv.x, fmaf(w6,Cv.y, a[k][2])))))));
                    a[k][3] = fmaf(w0,Bv.x, fmaf(w1,Bv.y, fmaf(w2,Bv.z, fmaf(w3,Bv.w,
                              fmaf(w4,Cv.x, fmaf(w5,Cv.y, fmaf(w6,Cv.z, a[k][3])))))));
                }
            }
        }
        if (have) {   // write-late: drain loads into the other LDS slot
            float* Q = pl[(zi+1) & 1];
            #pragma unroll
            for (int s = 0; s < 7; ++s)
                if (lw[s] >= 0) Q[lw[s]] = nv[s];
        }
        __syncthreads();
    }

    const float cbv = cbias[c];
    #pragma unroll
    for (int k = 0; k < 3; ++k) {
        const size_t v0 = (((size_t)b*D + (z0+k))*D + (y0 + ty))*D + 4*tx;
        y1[(v0+0)*C + c] = f2bf(a[k][0] + cbv);
        y1[(v0+1)*C + c] = f2bf(a[k][1] + cbv);
        y1[(v0+2)*C + c] = f2bf(a[k][2] + cbv);
        y1[(v0+3)*C + c] = f2bf(a[k][3] + cbv);
    }
}

// ---------------------------------------------------------------------------
// fc0 helper: 4 j-outputs for one voxel from x(16 f32) and y1(16 bf16).
// ---------------------------------------------------------------------------
__device__ __forceinline__ float4 fc0_vox(const float* __restrict__ x,
                                          const u16* __restrict__ y1,
                                          size_t v, const float4* wr, float4 h) {
    const float4* xp = (const float4*)(x + v*C);
    const ushort4* yp = (const ushort4*)(y1 + v*C);
    float4 x0 = xp[0], x1 = xp[1], x2 = xp[2], x3 = xp[3];
    ushort4 u0 = yp[0], u1 = yp[1], u2 = yp[2], u3 = yp[3];
    float4 q0 = {bf2f(u0.x), bf2f(u0.y), bf2f(u0.z), bf2f(u0.w)};
    float4 q1 = {bf2f(u1.x), bf2f(u1.y), bf2f(u1.z), bf2f(u1.w)};
    float4 q2 = {bf2f(u2.x), bf2f(u2.y), bf2f(u2.z), bf2f(u2.w)};
    float4 q3 = {bf2f(u3.x), bf2f(u3.y), bf2f(u3.z), bf2f(u3.w)};
#define STEP4(vv, base) \
    fma4(h, vv.x, wr[base+0]); fma4(h, vv.y, wr[base+1]); \
    fma4(h, vv.z, wr[base+2]); fma4(h, vv.w, wr[base+3]);
    STEP4(x0, 0)  STEP4(x1, 4)  STEP4(x2, 8)  STEP4(x3, 12)
    STEP4(q0, 16) STEP4(q1, 20) STEP4(q2, 24) STEP4(q3, 28)
#undef STEP4
    return h;
}

// ---------------------------------------------------------------------------
// k_fc0: h = [x|y1]@W0 + b0 -> bf16 h store + deterministic BN partials.
// ---------------------------------------------------------------------------
__global__ __launch_bounds__(256)
void k_fc0(const float* __restrict__ x, const u16* __restrict__ y1,
           const float* __restrict__ w0, const float* __restrict__ b0,
           u16* __restrict__ hb, float* __restrict__ partials) {
    __shared__ float red[2][8][H];
    const int t = threadIdx.x;
    const int j4 = t & 31, vg = t >> 5;
    const int j0 = j4 * 4;
    float4 wr[32];
    #pragma unroll
    for (int k = 0; k < 32; ++k) wr[k] = *(const float4*)(w0 + k*H + j0);
    const float4 bv = *(const float4*)(b0 + j0);
    float4 sum = {0.f,0.f,0.f,0.f}, sq = {0.f,0.f,0.f,0.f};
    const int vb = blockIdx.x * 256 + vg * 32;
    for (int i = 0; i < 32; ++i) {
        const size_t v = (size_t)(vb + i);
        float4 h = fc0_vox(x, y1, v, wr, bv);
        sum.x += h.x; sum.y += h.y; sum.z += h.z; sum.w += h.w;
        sq.x = fmaf(h.x,h.x,sq.x); sq.y = fmaf(h.y,h.y,sq.y);
        sq.z = fmaf(h.z,h.z,sq.z); sq.w = fmaf(h.w,h.w,sq.w);
        ushort4 hu = { f2bf(h.x), f2bf(h.y), f2bf(h.z), f2bf(h.w) };
        *(ushort4*)(hb + v*H + j0) = hu;
    }
    *(float4*)&red[0][vg][j0] = sum;
    *(float4*)&red[1][vg][j0] = sq;
    __syncthreads();
    const int stat = t >> 7, j = t & 127;
    float acc = 0.f;
    #pragma unroll
    for (int g = 0; g < 8; ++g) acc += red[stat][g][j];
    partials[(size_t)t * NB_FC + blockIdx.x] = acc;
}

// ---------------------------------------------------------------------------
__global__ __launch_bounds__(256)
void k_red(const float* __restrict__ partials, float* __restrict__ sums) {
    const int s = blockIdx.x, t = threadIdx.x;
    const float* row = partials + (size_t)s * NB_FC;
    float a = row[t] + row[t + 256] + row[t + 512];
    if (t + 768 < NB_FC) a += row[t + 768];
    __shared__ float l[256];
    l[t] = a; __syncthreads();
    if (t < 128) l[t] += l[t + 128];
    __syncthreads();
    if (t < 64) {
        float v = l[t] + l[t + 64];
        #pragma unroll
        for (int off = 32; off; off >>= 1) v += __shfl_down(v, off);
        if (t == 0) sums[s] = v;
    }
}

// ---------------------------------------------------------------------------
// k_apply: stream h (bf16), BN+ReLU -> LDS, fc1 vs LDS-transposed W1, masked
// residual; writes x' channels-last AND channel-major (for next conv).
// ---------------------------------------------------------------------------
__global__ __launch_bounds__(256)
void k_apply(const u16* __restrict__ hb, const float* __restrict__ x,
             const float* __restrict__ w1,
             const float* __restrict__ gamma, const float* __restrict__ beta,
             const float* __restrict__ sums, const int* __restrict__ mask,
             float* __restrict__ xo, float* __restrict__ xtn) {
    __shared__ float hs[16][132];
    __shared__ float w1t[16][132];   // [c][j]
    __shared__ float xs[16][17];
    const int t = threadIdx.x;
    const size_t vb = (size_t)blockIdx.x * 16;

    for (int idx = t; idx < H*C; idx += 256)
        w1t[idx & 15][idx >> 4] = w1[idx];          // w1[j][c] -> w1t[c][j]

    {   // phase A: BN-affine + ReLU into LDS
        const int j4 = t & 31, vh = t >> 5;
        const int j0 = j4 * 4;
        const float invN = 1.0f / (float)NVOX;
        const float4 sm = *(const float4*)(sums + j0);
        const float4 sQ = *(const float4*)(sums + H + j0);
        const float4 gm = *(const float4*)(gamma + j0);
        const float4 bt = *(const float4*)(beta + j0);
        float4 sc, sh;
        {
            float m0 = sm.x*invN, m1 = sm.y*invN, m2 = sm.z*invN, m3 = sm.w*invN;
            sc.x = gm.x * rsqrtf(fmaf(-m0,m0,sQ.x*invN) + BN_EPS);
            sc.y = gm.y * rsqrtf(fmaf(-m1,m1,sQ.y*invN) + BN_EPS);
            sc.z = gm.z * rsqrtf(fmaf(-m2,m2,sQ.z*invN) + BN_EPS);
            sc.w = gm.w * rsqrtf(fmaf(-m3,m3,sQ.w*invN) + BN_EPS);
            sh.x = bt.x - m0*sc.x; sh.y = bt.y - m1*sc.y;
            sh.z = bt.z - m2*sc.z; sh.w = bt.w - m3*sc.w;
        }
        #pragma unroll
        for (int rep = 0; rep < 2; ++rep) {
            const int vl = rep*8 + vh;
            ushort4 u = *(const ushort4*)(hb + (vb + vl)*H + j0);
            float4 hp;
            hp.x = fmaxf(0.f, fmaf(bf2f(u.x), sc.x, sh.x));
            hp.y = fmaxf(0.f, fmaf(bf2f(u.y), sc.y, sh.y));
            hp.z = fmaxf(0.f, fmaf(bf2f(u.z), sc.z, sh.z));
            hp.w = fmaxf(0.f, fmaf(bf2f(u.w), sc.w, sh.w));
            *(float4*)&hs[vl][j0] = hp;
        }
    }
    __syncthreads();
    {   // phase B: dx = h'@W1, masked residual, ch-0 freeze
        const int c = t & 15, vi = t >> 4;
        const size_t v = vb + vi;
        float4 acc = {0.f,0.f,0.f,0.f};
        #pragma unroll
        for (int j = 0; j < H; j += 4) {
            float4 hv = *(const float4*)&hs[vi][j];
            float4 wv = *(const float4*)&w1t[c][j];
            acc.x = fmaf(hv.x, wv.x, acc.x); acc.y = fmaf(hv.y, wv.y, acc.y);
            acc.z = fmaf(hv.z, wv.z, acc.z); acc.w = fmaf(hv.w, wv.w, acc.w);
        }
        const float dx = (acc.x + acc.y) + (acc.z + acc.w);
        const float m = (float)mask[v];
        const float xold = x[v*C + c];
        const float xn = (c == 0) ? xold : fmaf(dx, m, xold);
        xo[v*C + c] = xn;
        xs[c][vi] = xn;
    }
    __syncthreads();
    {   // emit channel-major copy for next step's conv
        const int c2 = t >> 4, i2 = t & 15;
        const size_t b = vb / D3, sp = vb % D3;
        xtn[(b*16 + c2)*(size_t)D3 + sp + i2] = xs[c2][i2];
    }
}

// ---------------------------------------------------------------------------
extern "C" void kernel_launch(void* const* d_in, const int* in_sizes, int n_in,
                              void* d_out, int out_size, void* d_ws, size_t ws_size,
                              hipStream_t stream) {
    const float* x_in = (const float*)d_in[0];
    const float* cw   = (const float*)d_in[1];
    const float* cb   = (const float*)d_in[2];
    const float* w0   = (const float*)d_in[3];
    const float* b0   = (const float*)d_in[4];
    const float* w1   = (const float*)d_in[5];
    const float* gm   = (const float*)d_in[6];
    const float* bt   = (const float*)d_in[7];
    const int*   mk   = (const int*)d_in[8];
    float* out = (float*)d_out;

    char* p = (char*)d_ws;
    u16*   y1       = (u16*)p;                 p += (size_t)NVOX * C * 2;   //  7.1MB
    u16*   hb       = (u16*)p;                 p += (size_t)NVOX * H * 2;   // 56.6MB
    float* xt       = (float*)p;               p += (size_t)NVOX * C * 4;   // 14.2MB
    float* xA       = (float*)p;               p += (size_t)NVOX * C * 4;   // 14.2MB
    float* partials = (float*)p;               p += (size_t)256 * NB_FC * 4;
    float* sums     = (float*)p;               p += 256 * 4;
    float* wt       = (float*)p;               // 343*16 floats

    k_xpose <<<NVOX/64, 256, 0, stream>>>(x_in, xt);
    k_wxpose<<<22,      256, 0, stream>>>(cw, wt);
    for (int s = 0; s < 8; ++s) {
        const float* src = (s == 0) ? x_in : ((s & 1) ? xA : out);
        float* dst = (s & 1) ? out : xA;               // s=7 -> d_out
        k_conv <<<1536,    CTPB, 0, stream>>>(xt, wt, cb, y1);
        k_fc0  <<<NB_FC,   256,  0, stream>>>(src, y1, w0, b0, hb, partials);
        k_red  <<<256,     256,  0, stream>>>(partials, sums);
        k_apply<<<NVOX/16, 256,  0, stream>>>(hb, src, w1, gm, bt, sums,
                                              mk + (size_t)s * NVOX, dst, xt);
    }
}

// Round 7
// 1383.989 us; speedup vs baseline: 1.0007x; 1.0007x over previous
//
#include <hip/hip_runtime.h>

#define D 48
#define C 16
#define H 128
#define D3 (D*D*D)
#define NVOX (2*D3)           // 221184
#define NB_FC (NVOX/256)      // 864
#define BN_EPS 1e-5f

typedef unsigned short u16;
typedef unsigned int   u32;

__device__ __forceinline__ float bf2f(u16 u) {
    union { u32 i; float f; } p; p.i = ((u32)u) << 16; return p.f;
}
__device__ __forceinline__ u16 f2bf(float f) {
    union { float f; u32 i; } p; p.f = f;
    u32 r = p.i + 0x7fffu + ((p.i >> 16) & 1u);   // RTNE
    return (u16)(r >> 16);
}
__device__ __forceinline__ int refl(int i) {
    return i < 0 ? -i : (i >= D ? 2*D - 2 - i : i);
}
__device__ __forceinline__ void fma4(float4& a, float s, const float4 w) {
    a.x = fmaf(s, w.x, a.x); a.y = fmaf(s, w.y, a.y);
    a.z = fmaf(s, w.z, a.z); a.w = fmaf(s, w.w, a.w);
}

// ---------------------------------------------------------------------------
// k_xpose: x channels-last [v][c] -> xt channel-major [b][c][s]. Once, step 0.
// ---------------------------------------------------------------------------
__global__ __launch_bounds__(256)
void k_xpose(const float* __restrict__ x, float* __restrict__ xt) {
    __shared__ float s[16][68];
    const int t = threadIdx.x;
    const size_t vb = (size_t)blockIdx.x * 64;
    float4 v4 = ((const float4*)(x + vb*16))[t];
    const int vv = t >> 2, c0 = (t & 3) * 4;
    s[c0+0][vv] = v4.x; s[c0+1][vv] = v4.y; s[c0+2][vv] = v4.z; s[c0+3][vv] = v4.w;
    __syncthreads();
    const int c = t >> 4, i0 = (t & 15) * 4;
    const size_t b = vb / D3, sp = vb % D3;
    float4 o = { s[c][i0], s[c][i0+1], s[c][i0+2], s[c][i0+3] };
    *(float4*)(xt + (b*16 + c)*(size_t)D3 + sp + i0) = o;
}

// ---------------------------------------------------------------------------
// k_wxpose: conv weights [kidx][c] -> wt[c][dy][dz][dx]. Run once.
// ---------------------------------------------------------------------------
__global__ __launch_bounds__(256)
void k_wxpose(const float* __restrict__ cw, float* __restrict__ wt) {
    int i = blockIdx.x * 256 + threadIdx.x;
    if (i < 343 * 16) {
        int kidx = i >> 4, c = i & 15;           // kidx = (dz*7+dy)*7+dx
        int dz = kidx / 49, dy = (kidx / 7) % 7, dx = kidx % 7;
        wt[((c*7 + dy)*7 + dz)*7 + dx] = cw[i];
    }
}

// ---------------------------------------------------------------------------
// k_conv v4: z-tile 3 (grid 1536 -> 6 blocks/CU, 18 waves/CU) + hoisted
// staging addressing (per-thread off/lds-word pairs precomputed once) +
// issue-early/write-late plane staging so global latency hides under FMAs.
// 12 register accumulators (3 z x 4 x) per thread; 9 planes per block.
// ---------------------------------------------------------------------------
#define CTPB 192
#define PLW (22*60)           // LDS words per plane buffer
__global__ __launch_bounds__(CTPB)
void k_conv(const float* __restrict__ xt, const float* __restrict__ wt,
            const float* __restrict__ cbias, u16* __restrict__ y1) {
    __shared__ float pl[2][PLW];      // 10560 B
    const int bid = blockIdx.x;
    const int zt = bid & 15;          // 16 z-tiles of 3
    const int yt = (bid >> 4) % 3;    // 3 y-tiles of 16
    const int c  = (bid / 48) & 15;
    const int b  = bid / 768;
    const int t  = threadIdx.x;
    const int tx = t % 12, ty = t / 12;
    const int y0 = yt * 16, z0 = zt * 3;
    const float* xb = xt + ((size_t)b*16 + c) * D3;
    const float* wc = wt + c * 343;   // [dy][dz][dx]

    // hoisted staging addressing: slot s covers idx = t + 192*s of the
    // 22x54 plane tile; off = global word offset in plane, lw = LDS word.
    int off[7], lw[7];
    #pragma unroll
    for (int s = 0; s < 7; ++s) {
        const int idx = t + CTPB*s;
        if (idx < 22*54) {
            const int r  = idx / 54;
            const int jc = idx - r*54;
            off[s] = refl(y0 - 3 + r)*D + refl(jc - 3);
            lw[s]  = r*60 + jc + 1;
        } else { off[s] = 0; lw[s] = -1; }
    }

    float a[3][4];
    #pragma unroll
    for (int k = 0; k < 3; ++k)
        a[k][0] = a[k][1] = a[k][2] = a[k][3] = 0.f;

    {   // prologue: stage plane z0-3
        const float* src = xb + (size_t)refl(z0-3) * (D*D);
        float* Q = pl[(z0-3) & 1];
        #pragma unroll
        for (int s = 0; s < 7; ++s)
            if (lw[s] >= 0) Q[lw[s]] = src[off[s]];
    }
    __syncthreads();

    for (int zi = z0 - 3; zi <= z0 + 5; ++zi) {
        // issue next plane's global loads early (latency hides under FMAs)
        float nv[7];
        const bool have = (zi < z0 + 5);
        if (have) {
            const float* src = xb + (size_t)refl(zi+1) * (D*D);
            #pragma unroll
            for (int s = 0; s < 7; ++s)
                if (lw[s] >= 0) nv[s] = src[off[s]];
        }
        const float* P = pl[zi & 1];
        #pragma unroll
        for (int dy = 0; dy < 7; ++dy) {
            const float* rp = P + (ty+dy)*60 + 4*tx;   // 16B aligned
            float4 A  = *(const float4*)rp;
            float4 Bv = *(const float4*)(rp + 4);
            float4 Cv = *(const float4*)(rp + 8);
            #pragma unroll
            for (int k = 0; k < 3; ++k) {        // output z = z0+k
                const int dz = zi - z0 - k + 3;  // block-uniform
                if (dz >= 0 && dz <= 6) {        // scalar branch
                    const float* wp = wc + (dy*7 + dz)*7;
                    float w0=wp[0], w1=wp[1], w2=wp[2], w3=wp[3];
                    float w4=wp[4], w5=wp[5], w6=wp[6];
                    a[k][0] = fmaf(w0,A.y, fmaf(w1,A.z, fmaf(w2,A.w, fmaf(w3,Bv.x,
                              fmaf(w4,Bv.y, fmaf(w5,Bv.z, fmaf(w6,Bv.w, a[k][0])))))));
                    a[k][1] = fmaf(w0,A.z, fmaf(w1,A.w, fmaf(w2,Bv.x, fmaf(w3,Bv.y,
                              fmaf(w4,Bv.z, fmaf(w5,Bv.w, fmaf(w6,Cv.x, a[k][1])))))));
                    a[k][2] = fmaf(w0,A.w, fmaf(w1,Bv.x, fmaf(w2,Bv.y, fmaf(w3,Bv.z,
                              fmaf(w4,Bv.w, fmaf(w5,Cv.x, fmaf(w6,Cv.y, a[k][2])))))));
                    a[k][3] = fmaf(w0,Bv.x, fmaf(w1,Bv.y, fmaf(w2,Bv.z, fmaf(w3,Bv.w,
                              fmaf(w4,Cv.x, fmaf(w5,Cv.y, fmaf(w6,Cv.z, a[k][3])))))));
                }
            }
        }
        if (have) {   // write-late: drain loads into the other LDS slot
            float* Q = pl[(zi+1) & 1];
            #pragma unroll
            for (int s = 0; s < 7; ++s)
                if (lw[s] >= 0) Q[lw[s]] = nv[s];
        }
        __syncthreads();
    }

    const float cbv = cbias[c];
    #pragma unroll
    for (int k = 0; k < 3; ++k) {
        const size_t v0 = (((size_t)b*D + (z0+k))*D + (y0 + ty))*D + 4*tx;
        y1[(v0+0)*C + c] = f2bf(a[k][0] + cbv);
        y1[(v0+1)*C + c] = f2bf(a[k][1] + cbv);
        y1[(v0+2)*C + c] = f2bf(a[k][2] + cbv);
        y1[(v0+3)*C + c] = f2bf(a[k][3] + cbv);
    }
}

// ---------------------------------------------------------------------------
// fc0 helper: 4 j-outputs for one voxel from x(16 f32) and y1(16 bf16).
// ---------------------------------------------------------------------------
__device__ __forceinline__ float4 fc0_vox(const float* __restrict__ x,
                                          const u16* __restrict__ y1,
                                          size_t v, const float4* wr, float4 h) {
    const float4* xp = (const float4*)(x + v*C);
    const ushort4* yp = (const ushort4*)(y1 + v*C);
    float4 x0 = xp[0], x1 = xp[1], x2 = xp[2], x3 = xp[3];
    ushort4 u0 = yp[0], u1 = yp[1], u2 = yp[2], u3 = yp[3];
    float4 q0 = {bf2f(u0.x), bf2f(u0.y), bf2f(u0.z), bf2f(u0.w)};
    float4 q1 = {bf2f(u1.x), bf2f(u1.y), bf2f(u1.z), bf2f(u1.w)};
    float4 q2 = {bf2f(u2.x), bf2f(u2.y), bf2f(u2.z), bf2f(u2.w)};
    float4 q3 = {bf2f(u3.x), bf2f(u3.y), bf2f(u3.z), bf2f(u3.w)};
#define STEP4(vv, base) \
    fma4(h, vv.x, wr[base+0]); fma4(h, vv.y, wr[base+1]); \
    fma4(h, vv.z, wr[base+2]); fma4(h, vv.w, wr[base+3]);
    STEP4(x0, 0)  STEP4(x1, 4)  STEP4(x2, 8)  STEP4(x3, 12)
    STEP4(q0, 16) STEP4(q1, 20) STEP4(q2, 24) STEP4(q3, 28)
#undef STEP4
    return h;
}

// ---------------------------------------------------------------------------
// k_fc0: h = [x|y1]@W0 + b0 -> bf16 h store + deterministic BN partials.
// ---------------------------------------------------------------------------
__global__ __launch_bounds__(256)
void k_fc0(const float* __restrict__ x, const u16* __restrict__ y1,
           const float* __restrict__ w0, const float* __restrict__ b0,
           u16* __restrict__ hb, float* __restrict__ partials) {
    __shared__ float red[2][8][H];
    const int t = threadIdx.x;
    const int j4 = t & 31, vg = t >> 5;
    const int j0 = j4 * 4;
    float4 wr[32];
    #pragma unroll
    for (int k = 0; k < 32; ++k) wr[k] = *(const float4*)(w0 + k*H + j0);
    const float4 bv = *(const float4*)(b0 + j0);
    float4 sum = {0.f,0.f,0.f,0.f}, sq = {0.f,0.f,0.f,0.f};
    const int vb = blockIdx.x * 256 + vg * 32;
    for (int i = 0; i < 32; ++i) {
        const size_t v = (size_t)(vb + i);
        float4 h = fc0_vox(x, y1, v, wr, bv);
        sum.x += h.x; sum.y += h.y; sum.z += h.z; sum.w += h.w;
        sq.x = fmaf(h.x,h.x,sq.x); sq.y = fmaf(h.y,h.y,sq.y);
        sq.z = fmaf(h.z,h.z,sq.z); sq.w = fmaf(h.w,h.w,sq.w);
        ushort4 hu = { f2bf(h.x), f2bf(h.y), f2bf(h.z), f2bf(h.w) };
        *(ushort4*)(hb + v*H + j0) = hu;
    }
    *(float4*)&red[0][vg][j0] = sum;
    *(float4*)&red[1][vg][j0] = sq;
    __syncthreads();
    const int stat = t >> 7, j = t & 127;
    float acc = 0.f;
    #pragma unroll
    for (int g = 0; g < 8; ++g) acc += red[stat][g][j];
    partials[(size_t)t * NB_FC + blockIdx.x] = acc;
}

// ---------------------------------------------------------------------------
__global__ __launch_bounds__(256)
void k_red(const float* __restrict__ partials, float* __restrict__ sums) {
    const int s = blockIdx.x, t = threadIdx.x;
    const float* row = partials + (size_t)s * NB_FC;
    float a = row[t] + row[t + 256] + row[t + 512];
    if (t + 768 < NB_FC) a += row[t + 768];
    __shared__ float l[256];
    l[t] = a; __syncthreads();
    if (t < 128) l[t] += l[t + 128];
    __syncthreads();
    if (t < 64) {
        float v = l[t] + l[t + 64];
        #pragma unroll
        for (int off = 32; off; off >>= 1) v += __shfl_down(v, off);
        if (t == 0) sums[s] = v;
    }
}

// ---------------------------------------------------------------------------
// k_apply: stream h (bf16), BN+ReLU -> LDS, fc1 vs LDS-transposed W1, masked
// residual; writes x' channels-last AND channel-major (for next conv).
// ---------------------------------------------------------------------------
__global__ __launch_bounds__(256)
void k_apply(const u16* __restrict__ hb, const float* __restrict__ x,
             const float* __restrict__ w1,
             const float* __restrict__ gamma, const float* __restrict__ beta,
             const float* __restrict__ sums, const int* __restrict__ mask,
             float* __restrict__ xo, float* __restrict__ xtn) {
    __shared__ float hs[16][132];
    __shared__ float w1t[16][132];   // [c][j]
    __shared__ float xs[16][17];
    const int t = threadIdx.x;
    const size_t vb = (size_t)blockIdx.x * 16;

    for (int idx = t; idx < H*C; idx += 256)
        w1t[idx & 15][idx >> 4] = w1[idx];          // w1[j][c] -> w1t[c][j]

    {   // phase A: BN-affine + ReLU into LDS
        const int j4 = t & 31, vh = t >> 5;
        const int j0 = j4 * 4;
        const float invN = 1.0f / (float)NVOX;
        const float4 sm = *(const float4*)(sums + j0);
        const float4 sQ = *(const float4*)(sums + H + j0);
        const float4 gm = *(const float4*)(gamma + j0);
        const float4 bt = *(const float4*)(beta + j0);
        float4 sc, sh;
        {
            float m0 = sm.x*invN, m1 = sm.y*invN, m2 = sm.z*invN, m3 = sm.w*invN;
            sc.x = gm.x * rsqrtf(fmaf(-m0,m0,sQ.x*invN) + BN_EPS);
            sc.y = gm.y * rsqrtf(fmaf(-m1,m1,sQ.y*invN) + BN_EPS);
            sc.z = gm.z * rsqrtf(fmaf(-m2,m2,sQ.z*invN) + BN_EPS);
            sc.w = gm.w * rsqrtf(fmaf(-m3,m3,sQ.w*invN) + BN_EPS);
            sh.x = bt.x - m0*sc.x; sh.y = bt.y - m1*sc.y;
            sh.z = bt.z - m2*sc.z; sh.w = bt.w - m3*sc.w;
        }
        #pragma unroll
        for (int rep = 0; rep < 2; ++rep) {
            const int vl = rep*8 + vh;
            ushort4 u = *(const ushort4*)(hb + (vb + vl)*H + j0);
            float4 hp;
            hp.x = fmaxf(0.f, fmaf(bf2f(u.x), sc.x, sh.x));
            hp.y = fmaxf(0.f, fmaf(bf2f(u.y), sc.y, sh.y));
            hp.z = fmaxf(0.f, fmaf(bf2f(u.z), sc.z, sh.z));
            hp.w = fmaxf(0.f, fmaf(bf2f(u.w), sc.w, sh.w));
            *(float4*)&hs[vl][j0] = hp;
        }
    }
    __syncthreads();
    {   // phase B: dx = h'@W1, masked residual, ch-0 freeze
        const int c = t & 15, vi = t >> 4;
        const size_t v = vb + vi;
        float4 acc = {0.f,0.f,0.f,0.f};
        #pragma unroll
        for (int j = 0; j < H; j += 4) {
            float4 hv = *(const float4*)&hs[vi][j];
            float4 wv = *(const float4*)&w1t[c][j];
            acc.x = fmaf(hv.x, wv.x, acc.x); acc.y = fmaf(hv.y, wv.y, acc.y);
            acc.z = fmaf(hv.z, wv.z, acc.z); acc.w = fmaf(hv.w, wv.w, acc.w);
        }
        const float dx = (acc.x + acc.y) + (acc.z + acc.w);
        const float m = (float)mask[v];
        const float xold = x[v*C + c];
        const float xn = (c == 0) ? xold : fmaf(dx, m, xold);
        xo[v*C + c] = xn;
        xs[c][vi] = xn;
    }
    __syncthreads();
    {   // emit channel-major copy for next step's conv
        const int c2 = t >> 4, i2 = t & 15;
        const size_t b = vb / D3, sp = vb % D3;
        xtn[(b*16 + c2)*(size_t)D3 + sp + i2] = xs[c2][i2];
    }
}

// ---------------------------------------------------------------------------
extern "C" void kernel_launch(void* const* d_in, const int* in_sizes, int n_in,
                              void* d_out, int out_size, void* d_ws, size_t ws_size,
                              hipStream_t stream) {
    const float* x_in = (const float*)d_in[0];
    const float* cw   = (const float*)d_in[1];
    const float* cb   = (const float*)d_in[2];
    const float* w0   = (const float*)d_in[3];
    const float* b0   = (const float*)d_in[4];
    const float* w1   = (const float*)d_in[5];
    const float* gm   = (const float*)d_in[6];
    const float* bt   = (const float*)d_in[7];
    const int*   mk   = (const int*)d_in[8];
    float* out = (float*)d_out;

    char* p = (char*)d_ws;
    u16*   y1       = (u16*)p;                 p += (size_t)NVOX * C * 2;   //  7.1MB
    u16*   hb       = (u16*)p;                 p += (size_t)NVOX * H * 2;   // 56.6MB
    float* xt       = (float*)p;               p += (size_t)NVOX * C * 4;   // 14.2MB
    float* xA       = (float*)p;               p += (size_t)NVOX * C * 4;   // 14.2MB
    float* partials = (float*)p;               p += (size_t)256 * NB_FC * 4;
    float* sums     = (float*)p;               p += 256 * 4;
    float* wt       = (float*)p;               // 343*16 floats

    k_xpose <<<NVOX/64, 256, 0, stream>>>(x_in, xt);
    k_wxpose<<<22,      256, 0, stream>>>(cw, wt);
    for (int s = 0; s < 8; ++s) {
        const float* src = (s == 0) ? x_in : ((s & 1) ? xA : out);
        float* dst = (s & 1) ? out : xA;               // s=7 -> d_out
        k_conv <<<1536,    CTPB, 0, stream>>>(xt, wt, cb, y1);
        k_fc0  <<<NB_FC,   256,  0, stream>>>(src, y1, w0, b0, hb, partials);
        k_red  <<<256,     256,  0, stream>>>(partials, sums);
        k_apply<<<NVOX/16, 256,  0, stream>>>(hb, src, w1, gm, bt, sums,
                                              mk + (size_t)s * NVOX, dst, xt);
    }
}

// Round 8
// 1380.755 us; speedup vs baseline: 1.0031x; 1.0023x over previous
//
#include <hip/hip_runtime.h>

#define D 48
#define C 16
#define H 128
#define D3 (D*D*D)
#define NVOX (2*D3)           // 221184
#define NB_FC (NVOX/256)      // 864
#define BN_EPS 1e-5f

typedef unsigned short u16;
typedef unsigned int   u32;

__device__ __forceinline__ float bf2f(u16 u) {
    union { u32 i; float f; } p; p.i = ((u32)u) << 16; return p.f;
}
__device__ __forceinline__ u16 f2bf(float f) {
    union { float f; u32 i; } p; p.f = f;
    u32 r = p.i + 0x7fffu + ((p.i >> 16) & 1u);   // RTNE
    return (u16)(r >> 16);
}
__device__ __forceinline__ int refl(int i) {
    return i < 0 ? -i : (i >= D ? 2*D - 2 - i : i);
}
__device__ __forceinline__ void fma4(float4& a, float s, const float4 w) {
    a.x = fmaf(s, w.x, a.x); a.y = fmaf(s, w.y, a.y);
    a.z = fmaf(s, w.z, a.z); a.w = fmaf(s, w.w, a.w);
}

// ---------------------------------------------------------------------------
// k_xpose: x channels-last [v][c] -> xt channel-major [b][c][s]. Once, step 0.
// ---------------------------------------------------------------------------
__global__ __launch_bounds__(256)
void k_xpose(const float* __restrict__ x, float* __restrict__ xt) {
    __shared__ float s[16][68];
    const int t = threadIdx.x;
    const size_t vb = (size_t)blockIdx.x * 64;
    float4 v4 = ((const float4*)(x + vb*16))[t];
    const int vv = t >> 2, c0 = (t & 3) * 4;
    s[c0+0][vv] = v4.x; s[c0+1][vv] = v4.y; s[c0+2][vv] = v4.z; s[c0+3][vv] = v4.w;
    __syncthreads();
    const int c = t >> 4, i0 = (t & 15) * 4;
    const size_t b = vb / D3, sp = vb % D3;
    float4 o = { s[c][i0], s[c][i0+1], s[c][i0+2], s[c][i0+3] };
    *(float4*)(xt + (b*16 + c)*(size_t)D3 + sp + i0) = o;
}

// ---------------------------------------------------------------------------
// k_wxpose: conv weights [kidx][c] -> wt[c][dy][dz][dx]. Run once.
// ---------------------------------------------------------------------------
__global__ __launch_bounds__(256)
void k_wxpose(const float* __restrict__ cw, float* __restrict__ wt) {
    int i = blockIdx.x * 256 + threadIdx.x;
    if (i < 343 * 16) {
        int kidx = i >> 4, c = i & 15;           // kidx = (dz*7+dy)*7+dx
        int dz = kidx / 49, dy = (kidx / 7) % 7, dx = kidx % 7;
        wt[((c*7 + dy)*7 + dz)*7 + dx] = cw[i];
    }
}

// ---------------------------------------------------------------------------
// k_conv v4: z-tile 3 (grid 1536 -> 6 blocks/CU, 18 waves/CU) + hoisted
// staging addressing (per-thread off/lds-word pairs precomputed once) +
// issue-early/write-late plane staging so global latency hides under FMAs.
// 12 register accumulators (3 z x 4 x) per thread; 9 planes per block.
// ---------------------------------------------------------------------------
#define CTPB 192
#define PLW (22*60)           // LDS words per plane buffer
__global__ __launch_bounds__(CTPB)
void k_conv(const float* __restrict__ xt, const float* __restrict__ wt,
            const float* __restrict__ cbias, u16* __restrict__ y1) {
    __shared__ float pl[2][PLW];      // 10560 B
    const int bid = blockIdx.x;
    const int zt = bid & 15;          // 16 z-tiles of 3
    const int yt = (bid >> 4) % 3;    // 3 y-tiles of 16
    const int c  = (bid / 48) & 15;
    const int b  = bid / 768;
    const int t  = threadIdx.x;
    const int tx = t % 12, ty = t / 12;
    const int y0 = yt * 16, z0 = zt * 3;
    const float* xb = xt + ((size_t)b*16 + c) * D3;
    const float* wc = wt + c * 343;   // [dy][dz][dx]

    // hoisted staging addressing: slot s covers idx = t + 192*s of the
    // 22x54 plane tile; off = global word offset in plane, lw = LDS word.
    int off[7], lw[7];
    #pragma unroll
    for (int s = 0; s < 7; ++s) {
        const int idx = t + CTPB*s;
        if (idx < 22*54) {
            const int r  = idx / 54;
            const int jc = idx - r*54;
            off[s] = refl(y0 - 3 + r)*D + refl(jc - 3);
            lw[s]  = r*60 + jc + 1;
        } else { off[s] = 0; lw[s] = -1; }
    }

    float a[3][4];
    #pragma unroll
    for (int k = 0; k < 3; ++k)
        a[k][0] = a[k][1] = a[k][2] = a[k][3] = 0.f;

    {   // prologue: stage plane z0-3
        const float* src = xb + (size_t)refl(z0-3) * (D*D);
        float* Q = pl[(z0-3) & 1];
        #pragma unroll
        for (int s = 0; s < 7; ++s)
            if (lw[s] >= 0) Q[lw[s]] = src[off[s]];
    }
    __syncthreads();

    for (int zi = z0 - 3; zi <= z0 + 5; ++zi) {
        // issue next plane's global loads early (latency hides under FMAs)
        float nv[7];
        const bool have = (zi < z0 + 5);
        if (have) {
            const float* src = xb + (size_t)refl(zi+1) * (D*D);
            #pragma unroll
            for (int s = 0; s < 7; ++s)
                if (lw[s] >= 0) nv[s] = src[off[s]];
        }
        const float* P = pl[zi & 1];
        #pragma unroll
        for (int dy = 0; dy < 7; ++dy) {
            const float* rp = P + (ty+dy)*60 + 4*tx;   // 16B aligned
            float4 A  = *(const float4*)rp;
            float4 Bv = *(const float4*)(rp + 4);
            float4 Cv = *(const float4*)(rp + 8);
            #pragma unroll
            for (int k = 0; k < 3; ++k) {        // output z = z0+k
                const int dz = zi - z0 - k + 3;  // block-uniform
                if (dz >= 0 && dz <= 6) {        // scalar branch
                    const float* wp = wc + (dy*7 + dz)*7;
                    float w0=wp[0], w1=wp[1], w2=wp[2], w3=wp[3];
                    float w4=wp[4], w5=wp[5], w6=wp[6];
                    a[k][0] = fmaf(w0,A.y, fmaf(w1,A.z, fmaf(w2,A.w, fmaf(w3,Bv.x,
                              fmaf(w4,Bv.y, fmaf(w5,Bv.z, fmaf(w6,Bv.w, a[k][0])))))));
                    a[k][1] = fmaf(w0,A.z, fmaf(w1,A.w, fmaf(w2,Bv.x, fmaf(w3,Bv.y,
                              fmaf(w4,Bv.z, fmaf(w5,Bv.w, fmaf(w6,Cv.x, a[k][1])))))));
                    a[k][2] = fmaf(w0,A.w, fmaf(w1,Bv.x, fmaf(w2,Bv.y, fmaf(w3,Bv.z,
                              fmaf(w4,Bv.w, fmaf(w5,Cv.x, fmaf(w6,Cv.y, a[k][2])))))));
                    a[k][3] = fmaf(w0,Bv.x, fmaf(w1,Bv.y, fmaf(w2,Bv.z, fmaf(w3,Bv.w,
                              fmaf(w4,Cv.x, fmaf(w5,Cv.y, fmaf(w6,Cv.z, a[k][3])))))));
                }
            }
        }
        if (have) {   // write-late: drain loads into the other LDS slot
            float* Q = pl[(zi+1) & 1];
            #pragma unroll
            for (int s = 0; s < 7; ++s)
                if (lw[s] >= 0) Q[lw[s]] = nv[s];
        }
        __syncthreads();
    }

    const float cbv = cbias[c];
    #pragma unroll
    for (int k = 0; k < 3; ++k) {
        const size_t v0 = (((size_t)b*D + (z0+k))*D + (y0 + ty))*D + 4*tx;
        y1[(v0+0)*C + c] = f2bf(a[k][0] + cbv);
        y1[(v0+1)*C + c] = f2bf(a[k][1] + cbv);
        y1[(v0+2)*C + c] = f2bf(a[k][2] + cbv);
        y1[(v0+3)*C + c] = f2bf(a[k][3] + cbv);
    }
}

// ---------------------------------------------------------------------------
// fc0 helper: 4 j-outputs for one voxel from x(16 f32) and y1(16 bf16).
// ---------------------------------------------------------------------------
__device__ __forceinline__ float4 fc0_vox(const float* __restrict__ x,
                                          const u16* __restrict__ y1,
                                          size_t v, const float4* wr, float4 h) {
    const float4* xp = (const float4*)(x + v*C);
    const ushort4* yp = (const ushort4*)(y1 + v*C);
    float4 x0 = xp[0], x1 = xp[1], x2 = xp[2], x3 = xp[3];
    ushort4 u0 = yp[0], u1 = yp[1], u2 = yp[2], u3 = yp[3];
    float4 q0 = {bf2f(u0.x), bf2f(u0.y), bf2f(u0.z), bf2f(u0.w)};
    float4 q1 = {bf2f(u1.x), bf2f(u1.y), bf2f(u1.z), bf2f(u1.w)};
    float4 q2 = {bf2f(u2.x), bf2f(u2.y), bf2f(u2.z), bf2f(u2.w)};
    float4 q3 = {bf2f(u3.x), bf2f(u3.y), bf2f(u3.z), bf2f(u3.w)};
#define STEP4(vv, base) \
    fma4(h, vv.x, wr[base+0]); fma4(h, vv.y, wr[base+1]); \
    fma4(h, vv.z, wr[base+2]); fma4(h, vv.w, wr[base+3]);
    STEP4(x0, 0)  STEP4(x1, 4)  STEP4(x2, 8)  STEP4(x3, 12)
    STEP4(q0, 16) STEP4(q1, 20) STEP4(q2, 24) STEP4(q3, 28)
#undef STEP4
    return h;
}

// ---------------------------------------------------------------------------
// k_fc0: h = [x|y1]@W0 + b0 -> bf16 h store + deterministic BN partials.
// ---------------------------------------------------------------------------
__global__ __launch_bounds__(256)
void k_fc0(const float* __restrict__ x, const u16* __restrict__ y1,
           const float* __restrict__ w0, const float* __restrict__ b0,
           u16* __restrict__ hb, float* __restrict__ partials) {
    __shared__ float red[2][8][H];
    const int t = threadIdx.x;
    const int j4 = t & 31, vg = t >> 5;
    const int j0 = j4 * 4;
    float4 wr[32];
    #pragma unroll
    for (int k = 0; k < 32; ++k) wr[k] = *(const float4*)(w0 + k*H + j0);
    const float4 bv = *(const float4*)(b0 + j0);
    float4 sum = {0.f,0.f,0.f,0.f}, sq = {0.f,0.f,0.f,0.f};
    const int vb = blockIdx.x * 256 + vg * 32;
    for (int i = 0; i < 32; ++i) {
        const size_t v = (size_t)(vb + i);
        float4 h = fc0_vox(x, y1, v, wr, bv);
        sum.x += h.x; sum.y += h.y; sum.z += h.z; sum.w += h.w;
        sq.x = fmaf(h.x,h.x,sq.x); sq.y = fmaf(h.y,h.y,sq.y);
        sq.z = fmaf(h.z,h.z,sq.z); sq.w = fmaf(h.w,h.w,sq.w);
        ushort4 hu = { f2bf(h.x), f2bf(h.y), f2bf(h.z), f2bf(h.w) };
        *(ushort4*)(hb + v*H + j0) = hu;
    }
    *(float4*)&red[0][vg][j0] = sum;
    *(float4*)&red[1][vg][j0] = sq;
    __syncthreads();
    const int stat = t >> 7, j = t & 127;
    float acc = 0.f;
    #pragma unroll
    for (int g = 0; g < 8; ++g) acc += red[stat][g][j];
    partials[(size_t)t * NB_FC + blockIdx.x] = acc;
}

// ---------------------------------------------------------------------------
__global__ __launch_bounds__(256)
void k_red(const float* __restrict__ partials, float* __restrict__ sums) {
    const int s = blockIdx.x, t = threadIdx.x;
    const float* row = partials + (size_t)s * NB_FC;
    float a = row[t] + row[t + 256] + row[t + 512];
    if (t + 768 < NB_FC) a += row[t + 768];
    __shared__ float l[256];
    l[t] = a; __syncthreads();
    if (t < 128) l[t] += l[t + 128];
    __syncthreads();
    if (t < 64) {
        float v = l[t] + l[t + 64];
        #pragma unroll
        for (int off = 32; off; off >>= 1) v += __shfl_down(v, off);
        if (t == 0) sums[s] = v;
    }
}

// ---------------------------------------------------------------------------
// k_apply: stream h (bf16), BN+ReLU -> LDS, fc1 vs LDS-transposed W1, masked
// residual; writes x' channels-last AND channel-major (for next conv).
// ---------------------------------------------------------------------------
__global__ __launch_bounds__(256)
void k_apply(const u16* __restrict__ hb, const float* __restrict__ x,
             const float* __restrict__ w1,
             const float* __restrict__ gamma, const float* __restrict__ beta,
             const float* __restrict__ sums, const int* __restrict__ mask,
             float* __restrict__ xo, float* __restrict__ xtn) {
    __shared__ float hs[16][132];
    __shared__ float w1t[16][132];   // [c][j]
    __shared__ float xs[16][17];
    const int t = threadIdx.x;
    const size_t vb = (size_t)blockIdx.x * 16;

    for (int idx = t; idx < H*C; idx += 256)
        w1t[idx & 15][idx >> 4] = w1[idx];          // w1[j][c] -> w1t[c][j]

    {   // phase A: BN-affine + ReLU into LDS
        const int j4 = t & 31, vh = t >> 5;
        const int j0 = j4 * 4;
        const float invN = 1.0f / (float)NVOX;
        const float4 sm = *(const float4*)(sums + j0);
        const float4 sQ = *(const float4*)(sums + H + j0);
        const float4 gm = *(const float4*)(gamma + j0);
        const float4 bt = *(const float4*)(beta + j0);
        float4 sc, sh;
        {
            float m0 = sm.x*invN, m1 = sm.y*invN, m2 = sm.z*invN, m3 = sm.w*invN;
            sc.x = gm.x * rsqrtf(fmaf(-m0,m0,sQ.x*invN) + BN_EPS);
            sc.y = gm.y * rsqrtf(fmaf(-m1,m1,sQ.y*invN) + BN_EPS);
            sc.z = gm.z * rsqrtf(fmaf(-m2,m2,sQ.z*invN) + BN_EPS);
            sc.w = gm.w * rsqrtf(fmaf(-m3,m3,sQ.w*invN) + BN_EPS);
            sh.x = bt.x - m0*sc.x; sh.y = bt.y - m1*sc.y;
            sh.z = bt.z - m2*sc.z; sh.w = bt.w - m3*sc.w;
        }
        #pragma unroll
        for (int rep = 0; rep < 2; ++rep) {
            const int vl = rep*8 + vh;
            ushort4 u = *(const ushort4*)(hb + (vb + vl)*H + j0);
            float4 hp;
            hp.x = fmaxf(0.f, fmaf(bf2f(u.x), sc.x, sh.x));
            hp.y = fmaxf(0.f, fmaf(bf2f(u.y), sc.y, sh.y));
            hp.z = fmaxf(0.f, fmaf(bf2f(u.z), sc.z, sh.z));
            hp.w = fmaxf(0.f, fmaf(bf2f(u.w), sc.w, sh.w));
            *(float4*)&hs[vl][j0] = hp;
        }
    }
    __syncthreads();
    {   // phase B: dx = h'@W1, masked residual, ch-0 freeze
        const int c = t & 15, vi = t >> 4;
        const size_t v = vb + vi;
        float4 acc = {0.f,0.f,0.f,0.f};
        #pragma unroll
        for (int j = 0; j < H; j += 4) {
            float4 hv = *(const float4*)&hs[vi][j];
            float4 wv = *(const float4*)&w1t[c][j];
            acc.x = fmaf(hv.x, wv.x, acc.x); acc.y = fmaf(hv.y, wv.y, acc.y);
            acc.z = fmaf(hv.z, wv.z, acc.z); acc.w = fmaf(hv.w, wv.w, acc.w);
        }
        const float dx = (acc.x + acc.y) + (acc.z + acc.w);
        const float m = (float)mask[v];
        const float xold = x[v*C + c];
        const float xn = (c == 0) ? xold : fmaf(dx, m, xold);
        xo[v*C + c] = xn;
        xs[c][vi] = xn;
    }
    __syncthreads();
    {   // emit channel-major copy for next step's conv
        const int c2 = t >> 4, i2 = t & 15;
        const size_t b = vb / D3, sp = vb % D3;
        xtn[(b*16 + c2)*(size_t)D3 + sp + i2] = xs[c2][i2];
    }
}

// ---------------------------------------------------------------------------
extern "C" void kernel_launch(void* const* d_in, const int* in_sizes, int n_in,
                              void* d_out, int out_size, void* d_ws, size_t ws_size,
                              hipStream_t stream) {
    const float* x_in = (const float*)d_in[0];
    const float* cw   = (const float*)d_in[1];
    const float* cb   = (const float*)d_in[2];
    const float* w0   = (const float*)d_in[3];
    const float* b0   = (const float*)d_in[4];
    const float* w1   = (const float*)d_in[5];
    const float* gm   = (const float*)d_in[6];
    const float* bt   = (const float*)d_in[7];
    const int*   mk   = (const int*)d_in[8];
    float* out = (float*)d_out;

    char* p = (char*)d_ws;
    u16*   y1       = (u16*)p;                 p += (size_t)NVOX * C * 2;   //  7.1MB
    u16*   hb       = (u16*)p;                 p += (size_t)NVOX * H * 2;   // 56.6MB
    float* xt       = (float*)p;               p += (size_t)NVOX * C * 4;   // 14.2MB
    float* xA       = (float*)p;               p += (size_t)NVOX * C * 4;   // 14.2MB
    float* partials = (float*)p;               p += (size_t)256 * NB_FC * 4;
    float* sums     = (float*)p;               p += 256 * 4;
    float* wt       = (float*)p;               // 343*16 floats

    k_xpose <<<NVOX/64, 256, 0, stream>>>(x_in, xt);
    k_wxpose<<<22,      256, 0, stream>>>(cw, wt);
    for (int s = 0; s < 8; ++s) {
        const float* src = (s == 0) ? x_in : ((s & 1) ? xA : out);
        float* dst = (s & 1) ? out : xA;               // s=7 -> d_out
        k_conv <<<1536,    CTPB, 0, stream>>>(xt, wt, cb, y1);
        k_fc0  <<<NB_FC,   256,  0, stream>>>(src, y1, w0, b0, hb, partials);
        k_red  <<<256,     256,  0, stream>>>(partials, sums);
        k_apply<<<NVOX/16, 256,  0, stream>>>(hb, src, w1, gm, bt, sums,
                                              mk + (size_t)s * NVOX, dst, xt);
    }
}